// Round 1
// baseline (1221.798 us; speedup 1.0000x reference)
//
#include <hip/hip_runtime.h>
#include <hip/hip_bf16.h>
#include <math.h>

#define N_NODES 50000
#define N_EDGES 800000
#define N_GRAPHS 64
#define HCD 256      // HID*HEADS
#define HIDD 64

// ---------------- CSR build ----------------

__global__ void zero_i32(int* __restrict__ p, int n) {
  int i = blockIdx.x * blockDim.x + threadIdx.x;
  if (i < n) p[i] = 0;
}

__global__ void hist_kernel(const int* __restrict__ dst, int* __restrict__ counts, int ne) {
  int i = blockIdx.x * blockDim.x + threadIdx.x;
  int stride = gridDim.x * blockDim.x;
  for (int e = i; e < ne; e += stride) atomicAdd(&counts[dst[e]], 1);
}

__global__ __launch_bounds__(1024) void scan_kernel(const int* __restrict__ counts,
                                                    int* __restrict__ offs, int n) {
  __shared__ int wsum[16];
  __shared__ int carry_s;
  int t = threadIdx.x;
  int lane = t & 63, wid = t >> 6;
  if (t == 0) carry_s = 0;
  __syncthreads();
  for (int base = 0; base < n; base += 1024) {
    int i = base + t;
    int v = (i < n) ? counts[i] : 0;
    int x = v;
    #pragma unroll
    for (int off = 1; off < 64; off <<= 1) {
      int tmp = __shfl_up(x, off);
      if (lane >= off) x += tmp;
    }
    if (lane == 63) wsum[wid] = x;
    __syncthreads();
    if (t < 16) {
      int ws = wsum[t];
      #pragma unroll
      for (int off = 1; off < 16; off <<= 1) {
        int tmp = __shfl_up(ws, off);
        if (lane >= off) ws += tmp;
      }
      wsum[t] = ws;  // inclusive scan of wave sums
    }
    __syncthreads();
    int waveoff = (wid == 0) ? 0 : wsum[wid - 1];
    int carry = carry_s;
    int incl = carry + waveoff + x;
    if (i < n) offs[i] = incl - v;  // exclusive
    __syncthreads();
    if (t == 1023) carry_s = incl;
    __syncthreads();
  }
  if (t == 0) offs[n] = carry_s;
}

__global__ void copy_i32(const int* __restrict__ a, int* __restrict__ b, int n) {
  int i = blockIdx.x * blockDim.x + threadIdx.x;
  if (i < n) b[i] = a[i];
}

__global__ void scatter_kernel(const int* __restrict__ src, const int* __restrict__ dst,
                               const float* __restrict__ ea, int* __restrict__ cursor,
                               int* __restrict__ ssrc, float* __restrict__ sea, int ne) {
  int i = blockIdx.x * blockDim.x + threadIdx.x;
  int stride = gridDim.x * blockDim.x;
  for (int e = i; e < ne; e += stride) {
    int d = dst[e];
    int pos = atomicAdd(&cursor[d], 1);
    ssrc[pos] = src[e];
    sea[pos] = ea[e];
  }
}

// ---------------- encoder ----------------

__global__ void encoder_kernel(const float* __restrict__ x, const float* __restrict__ w,
                               const float* __restrict__ b, float* __restrict__ h0, int n_nodes) {
  int idx = blockIdx.x * blockDim.x + threadIdx.x;
  if (idx >= n_nodes * HIDD) return;
  int n = idx >> 6, c = idx & 63;
  float acc = b[c];
  #pragma unroll
  for (int k = 0; k < 8; ++k) acc += x[n * 8 + k] * w[k * 64 + c];
  h0[idx] = fmaxf(acc, 0.f);
}

// ---------------- node transforms: xl = h@wl+bl, xr = h@wr+br ----------------
// block = 256 threads = 64 channel-groups (4ch each) x 4 node-groups (8 nodes each)
// tile = 32 nodes x 256 out-channels, both matrices

template<int K>
__global__ __launch_bounds__(256) void transform_kernel(
    const float* __restrict__ h,
    const float* __restrict__ wl, const float* __restrict__ bl,
    const float* __restrict__ wr, const float* __restrict__ br,
    float* __restrict__ xl, float* __restrict__ xr, int n_nodes)
{
  constexpr int NT = 32;
  __shared__ float hs[NT * K];
  int n0 = blockIdx.x * NT;
  for (int idx = threadIdx.x; idx < NT * K; idx += 256) {
    int i = idx / K, k = idx - i * K;
    int n = n0 + i;
    hs[idx] = (n < n_nodes) ? h[n * K + k] : 0.f;
  }
  __syncthreads();
  const int cx = threadIdx.x & 63;
  const int ny = threadIdx.x >> 6;
  float accL[8][4];
  float accR[8][4];
  #pragma unroll
  for (int i = 0; i < 8; ++i)
    #pragma unroll
    for (int j = 0; j < 4; ++j) { accL[i][j] = 0.f; accR[i][j] = 0.f; }
  const float* hrow = &hs[(ny * 8) * K];
  #pragma unroll 2
  for (int k = 0; k < K; ++k) {
    float4 wl4 = *(const float4*)&wl[k * 256 + 4 * cx];
    float4 wr4 = *(const float4*)&wr[k * 256 + 4 * cx];
    #pragma unroll
    for (int i = 0; i < 8; ++i) {
      float hv = hrow[i * K + k];
      accL[i][0] += hv * wl4.x; accL[i][1] += hv * wl4.y;
      accL[i][2] += hv * wl4.z; accL[i][3] += hv * wl4.w;
      accR[i][0] += hv * wr4.x; accR[i][1] += hv * wr4.y;
      accR[i][2] += hv * wr4.z; accR[i][3] += hv * wr4.w;
    }
  }
  float4 bl4 = *(const float4*)&bl[4 * cx];
  float4 br4 = *(const float4*)&br[4 * cx];
  #pragma unroll
  for (int i = 0; i < 8; ++i) {
    int n = n0 + ny * 8 + i;
    if (n < n_nodes) {
      float4 o;
      o.x = accL[i][0] + bl4.x; o.y = accL[i][1] + bl4.y;
      o.z = accL[i][2] + bl4.z; o.w = accL[i][3] + bl4.w;
      *(float4*)&xl[n * 256 + 4 * cx] = o;
      o.x = accR[i][0] + br4.x; o.y = accR[i][1] + br4.y;
      o.z = accR[i][2] + br4.z; o.w = accR[i][3] + br4.w;
      *(float4*)&xr[n * 256 + 4 * cx] = o;
    }
  }
}

// ---------------- fused edge logits + online softmax + aggregation ----------------
// one block per dst node; 256 threads; wave w == head w; channel hc == tid.
// online softmax over incoming edges; output = relu(sum alpha*xl[src] + bias)

__global__ __launch_bounds__(256) void gat_aggregate_kernel(
    const float* __restrict__ xl, const float* __restrict__ xr,
    const int* __restrict__ offs, const int* __restrict__ ssrc,
    const float* __restrict__ sea,
    const float* __restrict__ we, const float* __restrict__ att,
    const float* __restrict__ bias, float* __restrict__ out, int n_nodes)
{
  int n = blockIdx.x;
  if (n >= n_nodes) return;
  int hc = threadIdx.x;
  float xr_v = xr[n * HCD + hc];
  float we_v = we[hc];
  float att_v = att[hc];
  int beg = offs[n], end = offs[n + 1];
  float runmax = -INFINITY, den = 0.f, acc = 0.f;
  for (int j = beg; j < end; ++j) {
    int s = ssrc[j];
    float eav = sea[j];
    float xlv = xl[s * HCD + hc];
    float m = xlv + xr_v + eav * we_v;
    m = (m > 0.f) ? m : 0.2f * m;           // leaky_relu 0.2
    float p = m * att_v;
    #pragma unroll
    for (int off = 32; off >= 1; off >>= 1) p += __shfl_xor(p, off);
    float logit = p;                        // all 64 lanes hold head-h logit
    float nm = fmaxf(runmax, logit);
    float sc = __expf(runmax - nm);         // first iter: exp(-inf) = 0
    float wgt = __expf(logit - nm);
    den = den * sc + wgt;
    acc = acc * sc + wgt * xlv;
    runmax = nm;
  }
  float o = (end > beg) ? (acc / den) : 0.f;
  o += bias[hc];
  out[n * HCD + hc] = fmaxf(o, 0.f);
}

// ---------------- global mean pool (batch is sorted) ----------------

__device__ __forceinline__ int lbound(const int* __restrict__ a, int n, int key) {
  int lo = 0, hi = n;
  while (lo < hi) { int mid = (lo + hi) >> 1; if (a[mid] < key) lo = mid + 1; else hi = mid; }
  return lo;
}

__global__ __launch_bounds__(256) void pool_kernel(const float* __restrict__ h,
                                                   const int* __restrict__ batch,
                                                   float* __restrict__ gmean) {
  int g = blockIdx.x;
  __shared__ int sb, se;
  if (threadIdx.x == 0) {
    sb = lbound(batch, N_NODES, g);
    se = lbound(batch, N_NODES, g + 1);
  }
  __syncthreads();
  int beg = sb, end = se;
  float acc = 0.f;
  for (int n = beg; n < end; ++n) acc += h[n * HCD + threadIdx.x];
  float cnt = (float)((end - beg) > 1 ? (end - beg) : 1);
  gmean[g * HCD + threadIdx.x] = acc / cnt;
}

// ---------------- post MLP: Linear->LN->ReLU->Linear->ReLU->head ----------------

__global__ __launch_bounds__(128) void mlp_kernel(
    const float* __restrict__ gmean,
    const float* __restrict__ p1_w, const float* __restrict__ p1_b,
    const float* __restrict__ ln_g, const float* __restrict__ ln_b,
    const float* __restrict__ p2_w, const float* __restrict__ p2_b,
    const float* __restrict__ head_w, const float* __restrict__ head_b,
    float* __restrict__ out)
{
  int g = blockIdx.x, t = threadIdx.x;
  __shared__ float gv[256];
  __shared__ float zs[128];
  __shared__ float z2s[64];
  __shared__ float sums[2][2];
  gv[t] = gmean[g * 256 + t];
  gv[t + 128] = gmean[g * 256 + 128 + t];
  __syncthreads();
  float acc = p1_b[t];
  for (int k = 0; k < 256; ++k) acc += gv[k] * p1_w[k * 128 + t];
  // LayerNorm over 128
  float s1 = acc, s2 = acc * acc;
  #pragma unroll
  for (int off = 32; off >= 1; off >>= 1) {
    s1 += __shfl_xor(s1, off);
    s2 += __shfl_xor(s2, off);
  }
  int wid = t >> 6, lane = t & 63;
  if (lane == 0) { sums[wid][0] = s1; sums[wid][1] = s2; }
  __syncthreads();
  float S1 = sums[0][0] + sums[1][0];
  float S2 = sums[0][1] + sums[1][1];
  float mu = S1 * (1.f / 128.f);
  float var = S2 * (1.f / 128.f) - mu * mu;
  float rstd = rsqrtf(var + 1e-5f);
  float z = (acc - mu) * rstd * ln_g[t] + ln_b[t];
  zs[t] = fmaxf(z, 0.f);
  __syncthreads();
  if (t < 64) {
    float a2 = p2_b[t];
    for (int k = 0; k < 128; ++k) a2 += zs[k] * p2_w[k * 64 + t];
    z2s[t] = fmaxf(a2, 0.f);
  }
  __syncthreads();
  if (t < 64) {
    float p = z2s[t] * head_w[t];
    #pragma unroll
    for (int off = 32; off >= 1; off >>= 1) p += __shfl_xor(p, off);
    if (t == 0) out[g] = p + head_b[0];
  }
}

// ---------------- launch ----------------

extern "C" void kernel_launch(void* const* d_in, const int* in_sizes, int n_in,
                              void* d_out, int out_size, void* d_ws, size_t ws_size,
                              hipStream_t stream) {
  const float* x       = (const float*)d_in[0];
  const float* ea      = (const float*)d_in[1];
  const int*   eidx    = (const int*)d_in[2];
  const int*   batch   = (const int*)d_in[3];
  const float* enc_w   = (const float*)d_in[4];
  const float* enc_b   = (const float*)d_in[5];
  const float* g1_wl   = (const float*)d_in[6];
  const float* g1_bl   = (const float*)d_in[7];
  const float* g1_wr   = (const float*)d_in[8];
  const float* g1_br   = (const float*)d_in[9];
  const float* g1_we   = (const float*)d_in[10];
  const float* g1_att  = (const float*)d_in[11];
  const float* g1_bias = (const float*)d_in[12];
  const float* g2_wl   = (const float*)d_in[13];
  const float* g2_bl   = (const float*)d_in[14];
  const float* g2_wr   = (const float*)d_in[15];
  const float* g2_br   = (const float*)d_in[16];
  const float* g2_we   = (const float*)d_in[17];
  const float* g2_att  = (const float*)d_in[18];
  const float* g2_bias = (const float*)d_in[19];
  const float* p1_w    = (const float*)d_in[20];
  const float* p1_b    = (const float*)d_in[21];
  const float* ln_g    = (const float*)d_in[22];
  const float* ln_b    = (const float*)d_in[23];
  const float* p2_w    = (const float*)d_in[24];
  const float* p2_b    = (const float*)d_in[25];
  const float* head_w  = (const float*)d_in[26];
  const float* head_b  = (const float*)d_in[27];

  const int* src = eidx;
  const int* dst = eidx + N_EDGES;

  char* wsp = (char*)d_ws;
  size_t off = 0;
  auto alloc = [&](size_t bytes) -> void* {
    void* p = wsp + off;
    off += (bytes + 255) & ~(size_t)255;
    return p;
  };
  float* h0     = (float*)alloc((size_t)N_NODES * 64 * 4);
  float* hA     = (float*)alloc((size_t)N_NODES * 256 * 4);
  float* xl     = (float*)alloc((size_t)N_NODES * 256 * 4);
  float* xr     = (float*)alloc((size_t)N_NODES * 256 * 4);
  int*   counts = (int*)alloc((size_t)N_NODES * 4);
  int*   offs   = (int*)alloc((size_t)(N_NODES + 1) * 4);
  int*   cursor = (int*)alloc((size_t)N_NODES * 4);
  int*   ssrc   = (int*)alloc((size_t)N_EDGES * 4);
  float* seaf   = (float*)alloc((size_t)N_EDGES * 4);
  float* gmean  = (float*)alloc((size_t)N_GRAPHS * 256 * 4);

  // --- CSR by dst (built once, reused by both GAT layers) ---
  zero_i32<<<(N_NODES + 255) / 256, 256, 0, stream>>>(counts, N_NODES);
  hist_kernel<<<3125, 256, 0, stream>>>(dst, counts, N_EDGES);
  scan_kernel<<<1, 1024, 0, stream>>>(counts, offs, N_NODES);
  copy_i32<<<(N_NODES + 255) / 256, 256, 0, stream>>>(offs, cursor, N_NODES);
  scatter_kernel<<<3125, 256, 0, stream>>>(src, dst, ea, cursor, ssrc, seaf, N_EDGES);

  // --- encoder ---
  encoder_kernel<<<(N_NODES * 64 + 255) / 256, 256, 0, stream>>>(x, enc_w, enc_b, h0, N_NODES);

  // --- GAT layer 1 (in = 64) ---
  transform_kernel<64><<<(N_NODES + 31) / 32, 256, 0, stream>>>(
      h0, g1_wl, g1_bl, g1_wr, g1_br, xl, xr, N_NODES);
  gat_aggregate_kernel<<<N_NODES, 256, 0, stream>>>(
      xl, xr, offs, ssrc, seaf, g1_we, g1_att, g1_bias, hA, N_NODES);

  // --- GAT layer 2 (in = 256) ---
  transform_kernel<256><<<(N_NODES + 31) / 32, 256, 0, stream>>>(
      hA, g2_wl, g2_bl, g2_wr, g2_br, xl, xr, N_NODES);
  gat_aggregate_kernel<<<N_NODES, 256, 0, stream>>>(
      xl, xr, offs, ssrc, seaf, g2_we, g2_att, g2_bias, hA, N_NODES);

  // --- pool + MLP head ---
  pool_kernel<<<N_GRAPHS, 256, 0, stream>>>(hA, batch, gmean);
  mlp_kernel<<<N_GRAPHS, 128, 0, stream>>>(gmean, p1_w, p1_b, ln_g, ln_b,
                                           p2_w, p2_b, head_w, head_b, (float*)d_out);
}

// Round 4
// 767.872 us; speedup vs baseline: 1.5911x; 1.5911x over previous
//
#include <hip/hip_runtime.h>
#include <hip/hip_bf16.h>
#include <math.h>

#define N_NODES 50000
#define N_EDGES 800000
#define N_GRAPHS 64
#define HCD 256      // HID*HEADS
#define HIDD 64

// ---------------- CSR build ----------------

__global__ void zero_i32(int* __restrict__ p, int n) {
  int i = blockIdx.x * blockDim.x + threadIdx.x;
  if (i < n) p[i] = 0;
}

__global__ void hist_kernel(const int* __restrict__ dst, int* __restrict__ counts, int ne) {
  int i = blockIdx.x * blockDim.x + threadIdx.x;
  if (i < ne) atomicAdd(&counts[dst[i]], 1);
}

// block-level exclusive scan (256 elems per block), block totals to bsum
__global__ __launch_bounds__(256) void scan1_kernel(const int* __restrict__ counts,
                                                    int* __restrict__ offs,
                                                    int* __restrict__ bsum, int n) {
  int t = threadIdx.x, lane = t & 63, w = t >> 6;
  int i = blockIdx.x * 256 + t;
  int v = (i < n) ? counts[i] : 0;
  int x = v;
  #pragma unroll
  for (int off = 1; off < 64; off <<= 1) {
    int tmp = __shfl_up(x, off);
    if (lane >= off) x += tmp;
  }
  __shared__ int wsum[4], woff[4];
  if (lane == 63) wsum[w] = x;
  __syncthreads();
  if (t == 0) {
    int s = 0;
    #pragma unroll
    for (int k = 0; k < 4; ++k) { woff[k] = s; s += wsum[k]; }
    bsum[blockIdx.x] = s;
  }
  __syncthreads();
  if (i < n) offs[i] = woff[w] + x - v;
}

// exclusive scan of block sums (nblk <= 256) in place
__global__ __launch_bounds__(256) void scan2_kernel(int* __restrict__ bsum, int nblk) {
  int t = threadIdx.x, lane = t & 63, w = t >> 6;
  int v = (t < nblk) ? bsum[t] : 0;
  int x = v;
  #pragma unroll
  for (int off = 1; off < 64; off <<= 1) {
    int tmp = __shfl_up(x, off);
    if (lane >= off) x += tmp;
  }
  __shared__ int wsum[4], woff[4];
  if (lane == 63) wsum[w] = x;
  __syncthreads();
  if (t == 0) {
    int s = 0;
    #pragma unroll
    for (int k = 0; k < 4; ++k) { woff[k] = s; s += wsum[k]; }
  }
  __syncthreads();
  if (t < nblk) bsum[t] = woff[w] + x - v;
}

// add block bases; also writes offs[n] = total edge count
__global__ void scan3_kernel(int* __restrict__ offs, const int* __restrict__ bsum, int n) {
  int i = blockIdx.x * blockDim.x + threadIdx.x;
  if (i < n) offs[i] += bsum[i >> 8];
  else if (i == n) offs[n] = N_EDGES;
}

__global__ void copy_i32(const int* __restrict__ a, int* __restrict__ b, int n) {
  int i = blockIdx.x * blockDim.x + threadIdx.x;
  if (i < n) b[i] = a[i];
}

__global__ void scatter_kernel(const int* __restrict__ src, const int* __restrict__ dst,
                               const float* __restrict__ ea, int* __restrict__ cursor,
                               int* __restrict__ ssrc, float* __restrict__ sea, int ne) {
  int i = blockIdx.x * blockDim.x + threadIdx.x;
  if (i < ne) {
    int d = dst[i];
    int pos = atomicAdd(&cursor[d], 1);
    ssrc[pos] = src[i];
    sea[pos] = ea[i];
  }
}

// ---------------- encoder ----------------

__global__ void encoder_kernel(const float* __restrict__ x, const float* __restrict__ w,
                               const float* __restrict__ b, float* __restrict__ h0, int n_nodes) {
  int idx = blockIdx.x * blockDim.x + threadIdx.x;
  if (idx >= n_nodes * HIDD) return;
  int n = idx >> 6, c = idx & 63;
  float acc = b[c];
  #pragma unroll
  for (int k = 0; k < 8; ++k) acc += x[n * 8 + k] * w[k * 64 + c];
  h0[idx] = fmaxf(acc, 0.f);
}

// ---------------- node transforms: xl = h@wl+bl, xr = h@wr+br ----------------
// block = 256 threads: 64 channel-groups (4ch) x 4 node-groups (8 nodes)
// tile = 32 nodes x 256 out-channels, both matrices; LDS reads via float4 broadcast

template<int K>
__global__ __launch_bounds__(256) void transform_kernel(
    const float* __restrict__ h,
    const float* __restrict__ wl, const float* __restrict__ bl,
    const float* __restrict__ wr, const float* __restrict__ br,
    float* __restrict__ xl, float* __restrict__ xr, int n_nodes)
{
  constexpr int NT = 32;
  __shared__ float hs[NT * K];
  int n0 = blockIdx.x * NT;
  for (int idx4 = threadIdx.x; idx4 < NT * K / 4; idx4 += 256) {
    int i = idx4 / (K / 4), kq = idx4 - i * (K / 4);
    int n = n0 + i;
    float4 v = make_float4(0.f, 0.f, 0.f, 0.f);
    if (n < n_nodes) v = *(const float4*)&h[n * K + 4 * kq];
    *(float4*)&hs[i * K + 4 * kq] = v;
  }
  __syncthreads();
  const int cx = threadIdx.x & 63;
  const int ny = threadIdx.x >> 6;
  float accL[8][4];
  float accR[8][4];
  #pragma unroll
  for (int i = 0; i < 8; ++i)
    #pragma unroll
    for (int j = 0; j < 4; ++j) { accL[i][j] = 0.f; accR[i][j] = 0.f; }
  const float* hrow = &hs[(ny * 8) * K];
  for (int k4 = 0; k4 < K; k4 += 4) {
    float4 h4[8];
    #pragma unroll
    for (int i = 0; i < 8; ++i) h4[i] = *(const float4*)&hrow[i * K + k4];  // LDS broadcast
    #pragma unroll
    for (int kk = 0; kk < 4; ++kk) {
      float4 wl4 = *(const float4*)&wl[(k4 + kk) * 256 + 4 * cx];
      float4 wr4 = *(const float4*)&wr[(k4 + kk) * 256 + 4 * cx];
      #pragma unroll
      for (int i = 0; i < 8; ++i) {
        float hv = (kk == 0) ? h4[i].x : (kk == 1) ? h4[i].y : (kk == 2) ? h4[i].z : h4[i].w;
        accL[i][0] = fmaf(hv, wl4.x, accL[i][0]); accL[i][1] = fmaf(hv, wl4.y, accL[i][1]);
        accL[i][2] = fmaf(hv, wl4.z, accL[i][2]); accL[i][3] = fmaf(hv, wl4.w, accL[i][3]);
        accR[i][0] = fmaf(hv, wr4.x, accR[i][0]); accR[i][1] = fmaf(hv, wr4.y, accR[i][1]);
        accR[i][2] = fmaf(hv, wr4.z, accR[i][2]); accR[i][3] = fmaf(hv, wr4.w, accR[i][3]);
      }
    }
  }
  float4 bl4 = *(const float4*)&bl[4 * cx];
  float4 br4 = *(const float4*)&br[4 * cx];
  #pragma unroll
  for (int i = 0; i < 8; ++i) {
    int n = n0 + ny * 8 + i;
    if (n < n_nodes) {
      float4 o;
      o.x = accL[i][0] + bl4.x; o.y = accL[i][1] + bl4.y;
      o.z = accL[i][2] + bl4.z; o.w = accL[i][3] + bl4.w;
      *(float4*)&xl[n * 256 + 4 * cx] = o;
      o.x = accR[i][0] + br4.x; o.y = accR[i][1] + br4.y;
      o.z = accR[i][2] + br4.z; o.w = accR[i][3] + br4.w;
      *(float4*)&xr[n * 256 + 4 * cx] = o;
    }
  }
}

// ---------------- fused edge logits + online softmax + aggregation ----------------
// one block per dst node; 4 waves stride the node's edge list (1 wave = 1 edge).
// lane l owns channels 4l..4l+3 (all 4 heads per wave); logit reduce = 3 in-lane
// adds + 4-stage 16-lane butterfly. Flash-style cross-wave merge in LDS.

__global__ __launch_bounds__(256) void gat_aggregate_kernel(
    const float* __restrict__ xl, const float* __restrict__ xr,
    const int* __restrict__ offs, const int* __restrict__ ssrc,
    const float* __restrict__ sea,
    const float* __restrict__ we, const float* __restrict__ att,
    const float* __restrict__ bias, float* __restrict__ out, int n_nodes)
{
  int n = blockIdx.x;
  if (n >= n_nodes) return;
  int t = threadIdx.x, lane = t & 63, wv = t >> 6;
  const float4 xr4 = *(const float4*)&xr[n * HCD + 4 * lane];
  const float4 we4 = *(const float4*)&we[4 * lane];
  const float4 at4 = *(const float4*)&att[4 * lane];
  int beg = offs[n], end = offs[n + 1];
  float runmax = -INFINITY, den = 0.f;
  float4 acc = make_float4(0.f, 0.f, 0.f, 0.f);
  for (int j = beg + wv; j < end; j += 4) {
    int s = ssrc[j];
    float eav = sea[j];
    float4 xlv = *(const float4*)&xl[s * HCD + 4 * lane];
    float4 m;
    m.x = xlv.x + fmaf(eav, we4.x, xr4.x);
    m.y = xlv.y + fmaf(eav, we4.y, xr4.y);
    m.z = xlv.z + fmaf(eav, we4.z, xr4.z);
    m.w = xlv.w + fmaf(eav, we4.w, xr4.w);
    m.x = (m.x > 0.f) ? m.x : 0.2f * m.x;
    m.y = (m.y > 0.f) ? m.y : 0.2f * m.y;
    m.z = (m.z > 0.f) ? m.z : 0.2f * m.z;
    m.w = (m.w > 0.f) ? m.w : 0.2f * m.w;
    float p = fmaf(m.w, at4.w, fmaf(m.z, at4.z, fmaf(m.y, at4.y, m.x * at4.x)));
    #pragma unroll
    for (int off = 1; off < 16; off <<= 1) p += __shfl_xor(p, off);
    float nm = fmaxf(runmax, p);
    float sc = __expf(runmax - nm);   // first iter: exp(-inf)=0
    float wgt = __expf(p - nm);
    den = fmaf(den, sc, wgt);
    acc.x = fmaf(acc.x, sc, wgt * xlv.x);
    acc.y = fmaf(acc.y, sc, wgt * xlv.y);
    acc.z = fmaf(acc.z, sc, wgt * xlv.z);
    acc.w = fmaf(acc.w, sc, wgt * xlv.w);
    runmax = nm;
  }
  __shared__ float smax[4][64], sden[4][64];
  __shared__ float4 sacc[4][64];
  smax[wv][lane] = runmax; sden[wv][lane] = den; sacc[wv][lane] = acc;
  __syncthreads();
  if (wv == 0) {
    float m0 = smax[0][lane], m1 = smax[1][lane], m2 = smax[2][lane], m3 = smax[3][lane];
    float M = fmaxf(fmaxf(m0, m1), fmaxf(m2, m3));
    float4 a = make_float4(0.f, 0.f, 0.f, 0.f);
    if (M > -INFINITY) {
      float s0 = __expf(m0 - M), s1 = __expf(m1 - M), s2 = __expf(m2 - M), s3 = __expf(m3 - M);
      float d = sden[0][lane] * s0 + sden[1][lane] * s1 + sden[2][lane] * s2 + sden[3][lane] * s3;
      float4 a0 = sacc[0][lane], a1 = sacc[1][lane], a2 = sacc[2][lane], a3 = sacc[3][lane];
      a.x = a0.x * s0 + a1.x * s1 + a2.x * s2 + a3.x * s3;
      a.y = a0.y * s0 + a1.y * s1 + a2.y * s2 + a3.y * s3;
      a.z = a0.z * s0 + a1.z * s1 + a2.z * s2 + a3.z * s3;
      a.w = a0.w * s0 + a1.w * s1 + a2.w * s2 + a3.w * s3;
      float inv = 1.f / d;
      a.x *= inv; a.y *= inv; a.z *= inv; a.w *= inv;
    }
    float4 b4 = *(const float4*)&bias[4 * lane];
    float4 o;
    o.x = fmaxf(a.x + b4.x, 0.f);
    o.y = fmaxf(a.y + b4.y, 0.f);
    o.z = fmaxf(a.z + b4.z, 0.f);
    o.w = fmaxf(a.w + b4.w, 0.f);
    *(float4*)&out[n * HCD + 4 * lane] = o;
  }
}

// ---------------- global mean pool (batch is sorted) ----------------

__device__ __forceinline__ int lbound(const int* __restrict__ a, int n, int key) {
  int lo = 0, hi = n;
  while (lo < hi) { int mid = (lo + hi) >> 1; if (a[mid] < key) lo = mid + 1; else hi = mid; }
  return lo;
}

__global__ __launch_bounds__(256) void pool_kernel(const float* __restrict__ h,
                                                   const int* __restrict__ batch,
                                                   float* __restrict__ gmean) {
  int g = blockIdx.x;
  int t = threadIdx.x, lane = t & 63, wv = t >> 6;
  __shared__ int sb, se;
  if (t == 0) {
    sb = lbound(batch, N_NODES, g);
    se = lbound(batch, N_NODES, g + 1);
  }
  __syncthreads();
  int beg = sb, end = se;
  float4 acc = make_float4(0.f, 0.f, 0.f, 0.f);
  for (int n = beg + wv; n < end; n += 4) {
    float4 v = *(const float4*)&h[n * HCD + 4 * lane];
    acc.x += v.x; acc.y += v.y; acc.z += v.z; acc.w += v.w;
  }
  __shared__ float4 sacc[4][64];
  sacc[wv][lane] = acc;
  __syncthreads();
  if (wv == 0) {
    float4 a0 = sacc[0][lane], a1 = sacc[1][lane], a2 = sacc[2][lane], a3 = sacc[3][lane];
    float cnt = (float)((end - beg) > 1 ? (end - beg) : 1);
    float inv = 1.f / cnt;
    float4 o;
    o.x = (a0.x + a1.x + a2.x + a3.x) * inv;
    o.y = (a0.y + a1.y + a2.y + a3.y) * inv;
    o.z = (a0.z + a1.z + a2.z + a3.z) * inv;
    o.w = (a0.w + a1.w + a2.w + a3.w) * inv;
    *(float4*)&gmean[g * HCD + 4 * lane] = o;
  }
}

// ---------------- post MLP: Linear->LN->ReLU->Linear->ReLU->head ----------------

__global__ __launch_bounds__(128) void mlp_kernel(
    const float* __restrict__ gmean,
    const float* __restrict__ p1_w, const float* __restrict__ p1_b,
    const float* __restrict__ ln_g, const float* __restrict__ ln_b,
    const float* __restrict__ p2_w, const float* __restrict__ p2_b,
    const float* __restrict__ head_w, const float* __restrict__ head_b,
    float* __restrict__ out)
{
  int g = blockIdx.x, t = threadIdx.x;
  __shared__ float gv[256];
  __shared__ float zs[128];
  __shared__ float z2s[64];
  __shared__ float sums[2][2];
  gv[t] = gmean[g * 256 + t];
  gv[t + 128] = gmean[g * 256 + 128 + t];
  __syncthreads();
  float acc = p1_b[t];
  for (int k = 0; k < 256; ++k) acc += gv[k] * p1_w[k * 128 + t];
  float s1 = acc, s2 = acc * acc;
  #pragma unroll
  for (int off = 32; off >= 1; off >>= 1) {
    s1 += __shfl_xor(s1, off);
    s2 += __shfl_xor(s2, off);
  }
  int wid = t >> 6, lane = t & 63;
  if (lane == 0) { sums[wid][0] = s1; sums[wid][1] = s2; }
  __syncthreads();
  float S1 = sums[0][0] + sums[1][0];
  float S2 = sums[0][1] + sums[1][1];
  float mu = S1 * (1.f / 128.f);
  float var = S2 * (1.f / 128.f) - mu * mu;
  float rstd = rsqrtf(var + 1e-5f);
  float z = (acc - mu) * rstd * ln_g[t] + ln_b[t];
  zs[t] = fmaxf(z, 0.f);
  __syncthreads();
  if (t < 64) {
    float a2 = p2_b[t];
    for (int k = 0; k < 128; ++k) a2 += zs[k] * p2_w[k * 64 + t];
    z2s[t] = fmaxf(a2, 0.f);
  }
  __syncthreads();
  if (t < 64) {
    float p = z2s[t] * head_w[t];
    #pragma unroll
    for (int off = 32; off >= 1; off >>= 1) p += __shfl_xor(p, off);
    if (t == 0) out[g] = p + head_b[0];
  }
}

// ---------------- launch ----------------

extern "C" void kernel_launch(void* const* d_in, const int* in_sizes, int n_in,
                              void* d_out, int out_size, void* d_ws, size_t ws_size,
                              hipStream_t stream) {
  const float* x       = (const float*)d_in[0];
  const float* ea      = (const float*)d_in[1];
  const int*   eidx    = (const int*)d_in[2];
  const int*   batch   = (const int*)d_in[3];
  const float* enc_w   = (const float*)d_in[4];
  const float* enc_b   = (const float*)d_in[5];
  const float* g1_wl   = (const float*)d_in[6];
  const float* g1_bl   = (const float*)d_in[7];
  const float* g1_wr   = (const float*)d_in[8];
  const float* g1_br   = (const float*)d_in[9];
  const float* g1_we   = (const float*)d_in[10];
  const float* g1_att  = (const float*)d_in[11];
  const float* g1_bias = (const float*)d_in[12];
  const float* g2_wl   = (const float*)d_in[13];
  const float* g2_bl   = (const float*)d_in[14];
  const float* g2_wr   = (const float*)d_in[15];
  const float* g2_br   = (const float*)d_in[16];
  const float* g2_we   = (const float*)d_in[17];
  const float* g2_att  = (const float*)d_in[18];
  const float* g2_bias = (const float*)d_in[19];
  const float* p1_w    = (const float*)d_in[20];
  const float* p1_b    = (const float*)d_in[21];
  const float* ln_g    = (const float*)d_in[22];
  const float* ln_b    = (const float*)d_in[23];
  const float* p2_w    = (const float*)d_in[24];
  const float* p2_b    = (const float*)d_in[25];
  const float* head_w  = (const float*)d_in[26];
  const float* head_b  = (const float*)d_in[27];

  const int* src = eidx;
  const int* dst = eidx + N_EDGES;

  char* wsp = (char*)d_ws;
  size_t off = 0;
  auto alloc = [&](size_t bytes) -> void* {
    void* p = wsp + off;
    off += (bytes + 255) & ~(size_t)255;
    return p;
  };
  float* h0     = (float*)alloc((size_t)N_NODES * 64 * 4);
  float* hA     = (float*)alloc((size_t)N_NODES * 256 * 4);
  float* xl     = (float*)alloc((size_t)N_NODES * 256 * 4);
  float* xr     = (float*)alloc((size_t)N_NODES * 256 * 4);
  int*   counts = (int*)alloc((size_t)N_NODES * 4);
  int*   offs   = (int*)alloc((size_t)(N_NODES + 1) * 4);
  int*   cursor = (int*)alloc((size_t)N_NODES * 4);
  int*   bsum   = (int*)alloc((size_t)256 * 4);
  int*   ssrc   = (int*)alloc((size_t)N_EDGES * 4);
  float* seaf   = (float*)alloc((size_t)N_EDGES * 4);
  float* gmean  = (float*)alloc((size_t)N_GRAPHS * 256 * 4);

  const int NBLK = (N_NODES + 255) / 256;  // 196

  // --- CSR by dst (built once, reused by both GAT layers) ---
  zero_i32<<<NBLK, 256, 0, stream>>>(counts, N_NODES);
  hist_kernel<<<(N_EDGES + 255) / 256, 256, 0, stream>>>(dst, counts, N_EDGES);
  scan1_kernel<<<NBLK, 256, 0, stream>>>(counts, offs, bsum, N_NODES);
  scan2_kernel<<<1, 256, 0, stream>>>(bsum, NBLK);
  scan3_kernel<<<(N_NODES + 256) / 256, 256, 0, stream>>>(offs, bsum, N_NODES);
  copy_i32<<<NBLK, 256, 0, stream>>>(offs, cursor, N_NODES);
  scatter_kernel<<<(N_EDGES + 255) / 256, 256, 0, stream>>>(src, dst, ea, cursor, ssrc, seaf, N_EDGES);

  // --- encoder ---
  encoder_kernel<<<(N_NODES * 64 + 255) / 256, 256, 0, stream>>>(x, enc_w, enc_b, h0, N_NODES);

  // --- GAT layer 1 (in = 64) ---
  transform_kernel<64><<<(N_NODES + 31) / 32, 256, 0, stream>>>(
      h0, g1_wl, g1_bl, g1_wr, g1_br, xl, xr, N_NODES);
  gat_aggregate_kernel<<<N_NODES, 256, 0, stream>>>(
      xl, xr, offs, ssrc, seaf, g1_we, g1_att, g1_bias, hA, N_NODES);

  // --- GAT layer 2 (in = 256) ---
  transform_kernel<256><<<(N_NODES + 31) / 32, 256, 0, stream>>>(
      hA, g2_wl, g2_bl, g2_wr, g2_br, xl, xr, N_NODES);
  gat_aggregate_kernel<<<N_NODES, 256, 0, stream>>>(
      xl, xr, offs, ssrc, seaf, g2_we, g2_att, g2_bias, hA, N_NODES);

  // --- pool + MLP head ---
  pool_kernel<<<N_GRAPHS, 256, 0, stream>>>(hA, batch, gmean);
  mlp_kernel<<<N_GRAPHS, 128, 0, stream>>>(gmean, p1_w, p1_b, ln_g, ln_b,
                                           p2_w, p2_b, head_w, head_b, (float*)d_out);
}

// Round 6
// 755.525 us; speedup vs baseline: 1.6171x; 1.0163x over previous
//
#include <hip/hip_runtime.h>
#include <hip/hip_bf16.h>
#include <math.h>

#define N_NODES 50000
#define N_EDGES 800000
#define N_GRAPHS 64
#define HCD 256      // HID*HEADS
#define HIDD 64

// ---------------- CSR build ----------------

__global__ void zero_i32(int* __restrict__ p, int n) {
  int i = blockIdx.x * blockDim.x + threadIdx.x;
  if (i < n) p[i] = 0;
}

__global__ void hist_kernel(const int* __restrict__ dst, int* __restrict__ counts, int ne) {
  int i = blockIdx.x * blockDim.x + threadIdx.x;
  if (i < ne) atomicAdd(&counts[dst[i]], 1);
}

// block-level exclusive scan (256 elems per block), block totals to bsum
__global__ __launch_bounds__(256) void scan1_kernel(const int* __restrict__ counts,
                                                    int* __restrict__ offs,
                                                    int* __restrict__ bsum, int n) {
  int t = threadIdx.x, lane = t & 63, w = t >> 6;
  int i = blockIdx.x * 256 + t;
  int v = (i < n) ? counts[i] : 0;
  int x = v;
  #pragma unroll
  for (int off = 1; off < 64; off <<= 1) {
    int tmp = __shfl_up(x, off);
    if (lane >= off) x += tmp;
  }
  __shared__ int wsum[4], woff[4];
  if (lane == 63) wsum[w] = x;
  __syncthreads();
  if (t == 0) {
    int s = 0;
    #pragma unroll
    for (int k = 0; k < 4; ++k) { woff[k] = s; s += wsum[k]; }
    bsum[blockIdx.x] = s;
  }
  __syncthreads();
  if (i < n) offs[i] = woff[w] + x - v;
}

// exclusive scan of block sums (nblk <= 256) in place
__global__ __launch_bounds__(256) void scan2_kernel(int* __restrict__ bsum, int nblk) {
  int t = threadIdx.x, lane = t & 63, w = t >> 6;
  int v = (t < nblk) ? bsum[t] : 0;
  int x = v;
  #pragma unroll
  for (int off = 1; off < 64; off <<= 1) {
    int tmp = __shfl_up(x, off);
    if (lane >= off) x += tmp;
  }
  __shared__ int wsum[4], woff[4];
  if (lane == 63) wsum[w] = x;
  __syncthreads();
  if (t == 0) {
    int s = 0;
    #pragma unroll
    for (int k = 0; k < 4; ++k) { woff[k] = s; s += wsum[k]; }
  }
  __syncthreads();
  if (t < nblk) bsum[t] = woff[w] + x - v;
}

// add block bases; writes offs[n]=E and cursor copy (fused)
__global__ void scan3_kernel(int* __restrict__ offs, const int* __restrict__ bsum,
                             int* __restrict__ cursor, int n) {
  int i = blockIdx.x * blockDim.x + threadIdx.x;
  if (i < n) {
    int v = offs[i] + bsum[i >> 8];
    offs[i] = v;
    cursor[i] = v;
  } else if (i == n) {
    offs[n] = N_EDGES;
  }
}

__global__ void scatter_kernel(const int* __restrict__ src, const int* __restrict__ dst,
                               const float* __restrict__ ea, int* __restrict__ cursor,
                               int* __restrict__ ssrc, float* __restrict__ sea, int ne) {
  int i = blockIdx.x * blockDim.x + threadIdx.x;
  if (i < ne) {
    int d = dst[i];
    int pos = atomicAdd(&cursor[d], 1);
    ssrc[pos] = src[i];
    sea[pos] = ea[i];
  }
}

// ---------------- encoder ----------------

__global__ void encoder_kernel(const float* __restrict__ x, const float* __restrict__ w,
                               const float* __restrict__ b, float* __restrict__ h0, int n_nodes) {
  int idx = blockIdx.x * blockDim.x + threadIdx.x;
  if (idx >= n_nodes * HIDD) return;
  int n = idx >> 6, c = idx & 63;
  float acc = b[c];
  #pragma unroll
  for (int k = 0; k < 8; ++k) acc += x[n * 8 + k] * w[k * 64 + c];
  h0[idx] = fmaxf(acc, 0.f);
}

// ---------------- node transform: out = h@w + b (one matrix per block) ----------------
// grid = (tiles, 2): blockIdx.y==0 -> wl/xl, ==1 -> wr/xr.
// block = 256 threads: 64 channel-groups (4ch, cx) x 4 node-groups (8 nodes, ny).
// Per k: 8 LDS scalar broadcasts (h) + 32 FMA; next k's weight row prefetched into regs.
// acc=32 regs + h 8 + wc/wn 8 -> target VGPR < 64 (occupancy cliff at 64, m69).

template<int K>
__global__ __launch_bounds__(256) void transform_kernel(
    const float* __restrict__ h,
    const float* __restrict__ wl, const float* __restrict__ bl,
    const float* __restrict__ wr, const float* __restrict__ br,
    float* __restrict__ xl, float* __restrict__ xr, int n_nodes)
{
  constexpr int NT = 32;
  __shared__ float hs[NT * K];
  int n0 = blockIdx.x * NT;
  const float* __restrict__ w   = blockIdx.y ? wr : wl;
  const float* __restrict__ bb  = blockIdx.y ? br : bl;
  float* __restrict__ outp      = blockIdx.y ? xr : xl;

  for (int idx4 = threadIdx.x; idx4 < NT * K / 4; idx4 += 256) {
    int i = idx4 / (K / 4), kq = idx4 - i * (K / 4);
    int n = n0 + i;
    float4 v = make_float4(0.f, 0.f, 0.f, 0.f);
    if (n < n_nodes) v = *(const float4*)&h[n * K + 4 * kq];
    *(float4*)&hs[i * K + 4 * kq] = v;
  }
  __syncthreads();

  const int cx = threadIdx.x & 63;
  const int ny = threadIdx.x >> 6;
  float acc[8][4];
  #pragma unroll
  for (int i = 0; i < 8; ++i)
    #pragma unroll
    for (int j = 0; j < 4; ++j) acc[i][j] = 0.f;

  const float* hrow = &hs[(ny * 8) * K];
  float4 wc = *(const float4*)&w[4 * cx];          // k=0 row
  for (int k = 0; k < K; ++k) {
    float4 wn = wc;
    if (k + 1 < K) wn = *(const float4*)&w[(k + 1) * 256 + 4 * cx];  // prefetch
    #pragma unroll
    for (int i = 0; i < 8; ++i) {
      float hv = hrow[i * K + k];                  // LDS broadcast (wave-uniform addr)
      acc[i][0] = fmaf(hv, wc.x, acc[i][0]);
      acc[i][1] = fmaf(hv, wc.y, acc[i][1]);
      acc[i][2] = fmaf(hv, wc.z, acc[i][2]);
      acc[i][3] = fmaf(hv, wc.w, acc[i][3]);
    }
    wc = wn;
  }

  float4 b4 = *(const float4*)&bb[4 * cx];
  #pragma unroll
  for (int i = 0; i < 8; ++i) {
    int n = n0 + ny * 8 + i;
    if (n < n_nodes) {
      float4 o;
      o.x = acc[i][0] + b4.x; o.y = acc[i][1] + b4.y;
      o.z = acc[i][2] + b4.z; o.w = acc[i][3] + b4.w;
      *(float4*)&outp[n * 256 + 4 * cx] = o;
    }
  }
}

// ---------------- fused edge logits + online softmax + aggregation ----------------
// one block per dst node; 4 waves stride the node's edge list (1 wave = 1 edge).
// lane l owns channels 4l..4l+3 (all 4 heads per wave); logit reduce = 3 in-lane
// adds + 4-stage 16-lane butterfly. ssrc/sea prefetched 1 iter ahead to break the
// index->gather serial chain. Flash-style cross-wave merge in LDS.

__global__ __launch_bounds__(256) void gat_aggregate_kernel(
    const float* __restrict__ xl, const float* __restrict__ xr,
    const int* __restrict__ offs, const int* __restrict__ ssrc,
    const float* __restrict__ sea,
    const float* __restrict__ we, const float* __restrict__ att,
    const float* __restrict__ bias, float* __restrict__ out, int n_nodes)
{
  int n = blockIdx.x;
  if (n >= n_nodes) return;
  int t = threadIdx.x, lane = t & 63, wv = t >> 6;
  const float4 xr4 = *(const float4*)&xr[n * HCD + 4 * lane];
  const float4 we4 = *(const float4*)&we[4 * lane];
  const float4 at4 = *(const float4*)&att[4 * lane];
  int beg = offs[n], end = offs[n + 1];
  float runmax = -INFINITY, den = 0.f;
  float4 acc = make_float4(0.f, 0.f, 0.f, 0.f);

  int j = beg + wv;
  int s = (j < end) ? ssrc[j] : 0;
  float eav = (j < end) ? sea[j] : 0.f;
  while (j < end) {
    int jn = j + 4;
    int s2 = 0; float ea2 = 0.f;
    if (jn < end) { s2 = ssrc[jn]; ea2 = sea[jn]; }    // prefetch next index
    float4 xlv = *(const float4*)&xl[s * HCD + 4 * lane];
    float4 m;
    m.x = xlv.x + fmaf(eav, we4.x, xr4.x);
    m.y = xlv.y + fmaf(eav, we4.y, xr4.y);
    m.z = xlv.z + fmaf(eav, we4.z, xr4.z);
    m.w = xlv.w + fmaf(eav, we4.w, xr4.w);
    m.x = (m.x > 0.f) ? m.x : 0.2f * m.x;
    m.y = (m.y > 0.f) ? m.y : 0.2f * m.y;
    m.z = (m.z > 0.f) ? m.z : 0.2f * m.z;
    m.w = (m.w > 0.f) ? m.w : 0.2f * m.w;
    float p = fmaf(m.w, at4.w, fmaf(m.z, at4.z, fmaf(m.y, at4.y, m.x * at4.x)));
    #pragma unroll
    for (int off = 1; off < 16; off <<= 1) p += __shfl_xor(p, off);
    float nm = fmaxf(runmax, p);
    float sc = __expf(runmax - nm);   // first iter: exp(-inf)=0
    float wgt = __expf(p - nm);
    den = fmaf(den, sc, wgt);
    acc.x = fmaf(acc.x, sc, wgt * xlv.x);
    acc.y = fmaf(acc.y, sc, wgt * xlv.y);
    acc.z = fmaf(acc.z, sc, wgt * xlv.z);
    acc.w = fmaf(acc.w, sc, wgt * xlv.w);
    runmax = nm;
    s = s2; eav = ea2; j = jn;
  }

  __shared__ float smax[4][64], sden[4][64];
  __shared__ float4 sacc[4][64];
  smax[wv][lane] = runmax; sden[wv][lane] = den; sacc[wv][lane] = acc;
  __syncthreads();
  if (wv == 0) {
    float m0 = smax[0][lane], m1 = smax[1][lane], m2 = smax[2][lane], m3 = smax[3][lane];
    float M = fmaxf(fmaxf(m0, m1), fmaxf(m2, m3));
    float4 a = make_float4(0.f, 0.f, 0.f, 0.f);
    if (M > -INFINITY) {
      float s0 = __expf(m0 - M), s1 = __expf(m1 - M), s2 = __expf(m2 - M), s3 = __expf(m3 - M);
      float d = sden[0][lane] * s0 + sden[1][lane] * s1 + sden[2][lane] * s2 + sden[3][lane] * s3;
      float4 a0 = sacc[0][lane], a1 = sacc[1][lane], a2 = sacc[2][lane], a3 = sacc[3][lane];
      a.x = a0.x * s0 + a1.x * s1 + a2.x * s2 + a3.x * s3;
      a.y = a0.y * s0 + a1.y * s1 + a2.y * s2 + a3.y * s3;
      a.z = a0.z * s0 + a1.z * s1 + a2.z * s2 + a3.z * s3;
      a.w = a0.w * s0 + a1.w * s1 + a2.w * s2 + a3.w * s3;
      float inv = 1.f / d;
      a.x *= inv; a.y *= inv; a.z *= inv; a.w *= inv;
    }
    float4 b4 = *(const float4*)&bias[4 * lane];
    float4 o;
    o.x = fmaxf(a.x + b4.x, 0.f);
    o.y = fmaxf(a.y + b4.y, 0.f);
    o.z = fmaxf(a.z + b4.z, 0.f);
    o.w = fmaxf(a.w + b4.w, 0.f);
    *(float4*)&out[n * HCD + 4 * lane] = o;
  }
}

// ---------------- global mean pool (batch is sorted) ----------------

__device__ __forceinline__ int lbound(const int* __restrict__ a, int n, int key) {
  int lo = 0, hi = n;
  while (lo < hi) { int mid = (lo + hi) >> 1; if (a[mid] < key) lo = mid + 1; else hi = mid; }
  return lo;
}

__global__ __launch_bounds__(256) void pool_kernel(const float* __restrict__ h,
                                                   const int* __restrict__ batch,
                                                   float* __restrict__ gmean) {
  int g = blockIdx.x;
  int t = threadIdx.x, lane = t & 63, wv = t >> 6;
  __shared__ int sb, se;
  if (t == 0) {
    sb = lbound(batch, N_NODES, g);
    se = lbound(batch, N_NODES, g + 1);
  }
  __syncthreads();
  int beg = sb, end = se;
  float4 acc = make_float4(0.f, 0.f, 0.f, 0.f);
  for (int n = beg + wv; n < end; n += 4) {
    float4 v = *(const float4*)&h[n * HCD + 4 * lane];
    acc.x += v.x; acc.y += v.y; acc.z += v.z; acc.w += v.w;
  }
  __shared__ float4 sacc[4][64];
  sacc[wv][lane] = acc;
  __syncthreads();
  if (wv == 0) {
    float4 a0 = sacc[0][lane], a1 = sacc[1][lane], a2 = sacc[2][lane], a3 = sacc[3][lane];
    float cnt = (float)((end - beg) > 1 ? (end - beg) : 1);
    float inv = 1.f / cnt;
    float4 o;
    o.x = (a0.x + a1.x + a2.x + a3.x) * inv;
    o.y = (a0.y + a1.y + a2.y + a3.y) * inv;
    o.z = (a0.z + a1.z + a2.z + a3.z) * inv;
    o.w = (a0.w + a1.w + a2.w + a3.w) * inv;
    *(float4*)&gmean[g * HCD + 4 * lane] = o;
  }
}

// ---------------- post MLP: Linear->LN->ReLU->Linear->ReLU->head ----------------

__global__ __launch_bounds__(128) void mlp_kernel(
    const float* __restrict__ gmean,
    const float* __restrict__ p1_w, const float* __restrict__ p1_b,
    const float* __restrict__ ln_g, const float* __restrict__ ln_b,
    const float* __restrict__ p2_w, const float* __restrict__ p2_b,
    const float* __restrict__ head_w, const float* __restrict__ head_b,
    float* __restrict__ out)
{
  int g = blockIdx.x, t = threadIdx.x;
  __shared__ float gv[256];
  __shared__ float zs[128];
  __shared__ float z2s[64];
  __shared__ float sums[2][2];
  gv[t] = gmean[g * 256 + t];
  gv[t + 128] = gmean[g * 256 + 128 + t];
  __syncthreads();
  float acc = p1_b[t];
  for (int k = 0; k < 256; ++k) acc += gv[k] * p1_w[k * 128 + t];
  float s1 = acc, s2 = acc * acc;
  #pragma unroll
  for (int off = 32; off >= 1; off >>= 1) {
    s1 += __shfl_xor(s1, off);
    s2 += __shfl_xor(s2, off);
  }
  int wid = t >> 6, lane = t & 63;
  if (lane == 0) { sums[wid][0] = s1; sums[wid][1] = s2; }
  __syncthreads();
  float S1 = sums[0][0] + sums[1][0];
  float S2 = sums[0][1] + sums[1][1];
  float mu = S1 * (1.f / 128.f);
  float var = S2 * (1.f / 128.f) - mu * mu;
  float rstd = rsqrtf(var + 1e-5f);
  float z = (acc - mu) * rstd * ln_g[t] + ln_b[t];
  zs[t] = fmaxf(z, 0.f);
  __syncthreads();
  if (t < 64) {
    float a2 = p2_b[t];
    for (int k = 0; k < 128; ++k) a2 += zs[k] * p2_w[k * 64 + t];
    z2s[t] = fmaxf(a2, 0.f);
  }
  __syncthreads();
  if (t < 64) {
    float p = z2s[t] * head_w[t];
    #pragma unroll
    for (int off = 32; off >= 1; off >>= 1) p += __shfl_xor(p, off);
    if (t == 0) out[g] = p + head_b[0];
  }
}

// ---------------- launch ----------------

extern "C" void kernel_launch(void* const* d_in, const int* in_sizes, int n_in,
                              void* d_out, int out_size, void* d_ws, size_t ws_size,
                              hipStream_t stream) {
  const float* x       = (const float*)d_in[0];
  const float* ea      = (const float*)d_in[1];
  const int*   eidx    = (const int*)d_in[2];
  const int*   batch   = (const int*)d_in[3];
  const float* enc_w   = (const float*)d_in[4];
  const float* enc_b   = (const float*)d_in[5];
  const float* g1_wl   = (const float*)d_in[6];
  const float* g1_bl   = (const float*)d_in[7];
  const float* g1_wr   = (const float*)d_in[8];
  const float* g1_br   = (const float*)d_in[9];
  const float* g1_we   = (const float*)d_in[10];
  const float* g1_att  = (const float*)d_in[11];
  const float* g1_bias = (const float*)d_in[12];
  const float* g2_wl   = (const float*)d_in[13];
  const float* g2_bl   = (const float*)d_in[14];
  const float* g2_wr   = (const float*)d_in[15];
  const float* g2_br   = (const float*)d_in[16];
  const float* g2_we   = (const float*)d_in[17];
  const float* g2_att  = (const float*)d_in[18];
  const float* g2_bias = (const float*)d_in[19];
  const float* p1_w    = (const float*)d_in[20];
  const float* p1_b    = (const float*)d_in[21];
  const float* ln_g    = (const float*)d_in[22];
  const float* ln_b    = (const float*)d_in[23];
  const float* p2_w    = (const float*)d_in[24];
  const float* p2_b    = (const float*)d_in[25];
  const float* head_w  = (const float*)d_in[26];
  const float* head_b  = (const float*)d_in[27];

  const int* src = eidx;
  const int* dst = eidx + N_EDGES;

  char* wsp = (char*)d_ws;
  size_t off = 0;
  auto alloc = [&](size_t bytes) -> void* {
    void* p = wsp + off;
    off += (bytes + 255) & ~(size_t)255;
    return p;
  };
  float* h0     = (float*)alloc((size_t)N_NODES * 64 * 4);
  float* hA     = (float*)alloc((size_t)N_NODES * 256 * 4);
  float* xl     = (float*)alloc((size_t)N_NODES * 256 * 4);
  float* xr     = (float*)alloc((size_t)N_NODES * 256 * 4);
  int*   counts = (int*)alloc((size_t)N_NODES * 4);
  int*   offs   = (int*)alloc((size_t)(N_NODES + 1) * 4);
  int*   cursor = (int*)alloc((size_t)N_NODES * 4);
  int*   bsum   = (int*)alloc((size_t)256 * 4);
  int*   ssrc   = (int*)alloc((size_t)N_EDGES * 4);
  float* seaf   = (float*)alloc((size_t)N_EDGES * 4);
  float* gmean  = (float*)alloc((size_t)N_GRAPHS * 256 * 4);

  const int NBLK = (N_NODES + 255) / 256;  // 196

  // --- CSR by dst (built once, reused by both GAT layers) ---
  zero_i32<<<NBLK, 256, 0, stream>>>(counts, N_NODES);
  hist_kernel<<<(N_EDGES + 255) / 256, 256, 0, stream>>>(dst, counts, N_EDGES);
  scan1_kernel<<<NBLK, 256, 0, stream>>>(counts, offs, bsum, N_NODES);
  scan2_kernel<<<1, 256, 0, stream>>>(bsum, NBLK);
  scan3_kernel<<<(N_NODES + 256) / 256, 256, 0, stream>>>(offs, bsum, cursor, N_NODES);
  scatter_kernel<<<(N_EDGES + 255) / 256, 256, 0, stream>>>(src, dst, ea, cursor, ssrc, seaf, N_EDGES);

  // --- encoder ---
  encoder_kernel<<<(N_NODES * 64 + 255) / 256, 256, 0, stream>>>(x, enc_w, enc_b, h0, N_NODES);

  const dim3 tgrid((N_NODES + 31) / 32, 2);

  // --- GAT layer 1 (in = 64) ---
  transform_kernel<64><<<tgrid, 256, 0, stream>>>(
      h0, g1_wl, g1_bl, g1_wr, g1_br, xl, xr, N_NODES);
  gat_aggregate_kernel<<<N_NODES, 256, 0, stream>>>(
      xl, xr, offs, ssrc, seaf, g1_we, g1_att, g1_bias, hA, N_NODES);

  // --- GAT layer 2 (in = 256) ---
  transform_kernel<256><<<tgrid, 256, 0, stream>>>(
      hA, g2_wl, g2_bl, g2_wr, g2_br, xl, xr, N_NODES);
  gat_aggregate_kernel<<<N_NODES, 256, 0, stream>>>(
      xl, xr, offs, ssrc, seaf, g2_we, g2_att, g2_bias, hA, N_NODES);

  // --- pool + MLP head ---
  pool_kernel<<<N_GRAPHS, 256, 0, stream>>>(hA, batch, gmean);
  mlp_kernel<<<N_GRAPHS, 128, 0, stream>>>(gmean, p1_w, p1_b, ln_g, ln_b,
                                           p2_w, p2_b, head_w, head_b, (float*)d_out);
}